// Round 11
// baseline (39.688 us; speedup 1.0000x reference)
//
#include <hip/hip_runtime.h>
#include <math.h>

// Problem constants (from reference):
constexpr int Bn = 1024;
constexpr int S  = 512;
constexpr int H  = 768;
constexpr int D1 = 128;
constexpr int HV = H / 4;     // 192 float4 per feature row

// Single fused kernel. Block = 4 examples, 768 threads (12 waves), grid 256.
// Phase A: waves 0-5 pool the 4 spans; waves 6-11 CLS-half W1 dots (from
//          feat row 0, broadcast global loads) -- concurrent, disjoint pipes.
// Phase B: all waves CRC-half W1 dots from LDS means.
// Phase C: finalize relu/W2/sigmoid in-block. No workspace, no 2nd launch.
__global__ __launch_bounds__(768) void fused_all(
    const float* __restrict__ feat, const int* __restrict__ start,
    const int* __restrict__ endp, const float* __restrict__ W1,
    const float* __restrict__ b1, const float* __restrict__ W2,
    const float* __restrict__ b2, float* __restrict__ out) {
  __shared__ float g_crc[4][H];      // 12 KB: span means
  __shared__ float part[9][4][D1];   // 18 KB: [0..2]=CLS subs, [3..8]=CRC subs

  const int t = threadIdx.x;
  const int e0 = blockIdx.x * 4;

  if (t < 384) {
    // ---- pool: 96 threads per example; thread owns float4 cols c and c+96.
    const int ex = t / 96;
    const int c  = t - ex * 96;
    const int b  = e0 + ex;
    const float4* base =
        reinterpret_cast<const float4*>(feat) + (size_t)b * (S * HV);
    const int s0 = start[b];
    const int s1 = endp[b];
    float4 A0{0,0,0,0}, A1{0,0,0,0}, A2{0,0,0,0}, A3{0,0,0,0};
    float4 B0{0,0,0,0}, B1{0,0,0,0}, B2{0,0,0,0}, B3{0,0,0,0};
    int s = s0;
    for (; s + 3 < s1; s += 4) {   // 8 independent loads in flight
      float4 u0 = base[(size_t)(s + 0) * HV + c];
      float4 v0 = base[(size_t)(s + 0) * HV + c + 96];
      float4 u1 = base[(size_t)(s + 1) * HV + c];
      float4 v1 = base[(size_t)(s + 1) * HV + c + 96];
      float4 u2 = base[(size_t)(s + 2) * HV + c];
      float4 v2 = base[(size_t)(s + 2) * HV + c + 96];
      float4 u3 = base[(size_t)(s + 3) * HV + c];
      float4 v3 = base[(size_t)(s + 3) * HV + c + 96];
      A0.x += u0.x; A0.y += u0.y; A0.z += u0.z; A0.w += u0.w;
      B0.x += v0.x; B0.y += v0.y; B0.z += v0.z; B0.w += v0.w;
      A1.x += u1.x; A1.y += u1.y; A1.z += u1.z; A1.w += u1.w;
      B1.x += v1.x; B1.y += v1.y; B1.z += v1.z; B1.w += v1.w;
      A2.x += u2.x; A2.y += u2.y; A2.z += u2.z; A2.w += u2.w;
      B2.x += v2.x; B2.y += v2.y; B2.z += v2.z; B2.w += v2.w;
      A3.x += u3.x; A3.y += u3.y; A3.z += u3.z; A3.w += u3.w;
      B3.x += v3.x; B3.y += v3.y; B3.z += v3.z; B3.w += v3.w;
    }
    for (; s < s1; ++s) {
      float4 u = base[(size_t)s * HV + c];
      float4 v = base[(size_t)s * HV + c + 96];
      A0.x += u.x; A0.y += u.y; A0.z += u.z; A0.w += u.w;
      B0.x += v.x; B0.y += v.y; B0.z += v.z; B0.w += v.w;
    }
    const float inv = 1.0f / (float)(s1 - s0);
    float4 rA, rB;
    rA.x = ((A0.x + A1.x) + (A2.x + A3.x)) * inv;
    rA.y = ((A0.y + A1.y) + (A2.y + A3.y)) * inv;
    rA.z = ((A0.z + A1.z) + (A2.z + A3.z)) * inv;
    rA.w = ((A0.w + A1.w) + (A2.w + A3.w)) * inv;
    rB.x = ((B0.x + B1.x) + (B2.x + B3.x)) * inv;
    rB.y = ((B0.y + B1.y) + (B2.y + B3.y)) * inv;
    rB.z = ((B0.z + B1.z) + (B2.z + B3.z)) * inv;
    rB.w = ((B0.w + B1.w) + (B2.w + B3.w)) * inv;
    reinterpret_cast<float4*>(&g_crc[ex][0])[c] = rA;
    reinterpret_cast<float4*>(&g_crc[ex][0])[c + 96] = rB;
  } else {
    // ---- CLS-half head: thread = (k, sub in {0,1,2} -> 256-row d-seg).
    const int t2 = t - 384;
    const int k = t2 & (D1 - 1);
    const int sub = t2 >> 7;
    const int d0 = sub * 256;
    const float* Wc = W1 + (size_t)d0 * D1 + k;
    const float* f0 = feat + (size_t)(e0 + 0) * S * H + d0;  // row 0
    const float* f1 = feat + (size_t)(e0 + 1) * S * H + d0;
    const float* f2 = feat + (size_t)(e0 + 2) * S * H + d0;
    const float* f3 = feat + (size_t)(e0 + 3) * S * H + d0;
    float a0 = 0.f, a1 = 0.f, a2 = 0.f, a3 = 0.f;
    #pragma unroll 4
    for (int d = 0; d < 256; d += 4) {
      float w0 = Wc[(size_t)(d + 0) * D1];
      float w1 = Wc[(size_t)(d + 1) * D1];
      float w2 = Wc[(size_t)(d + 2) * D1];
      float w3 = Wc[(size_t)(d + 3) * D1];
      float4 g0 = *reinterpret_cast<const float4*>(f0 + d);  // broadcast, L2
      float4 g1 = *reinterpret_cast<const float4*>(f1 + d);
      float4 g2 = *reinterpret_cast<const float4*>(f2 + d);
      float4 g3 = *reinterpret_cast<const float4*>(f3 + d);
      a0 += g0.x * w0 + g0.y * w1 + g0.z * w2 + g0.w * w3;
      a1 += g1.x * w0 + g1.y * w1 + g1.z * w2 + g1.w * w3;
      a2 += g2.x * w0 + g2.y * w1 + g2.z * w2 + g2.w * w3;
      a3 += g3.x * w0 + g3.y * w1 + g3.z * w2 + g3.w * w3;
    }
    part[sub][0][k] = a0;
    part[sub][1][k] = a1;
    part[sub][2][k] = a2;
    part[sub][3][k] = a3;
  }
  __syncthreads();

  // ---- CRC-half head: all 768 threads = (k, sub in [0,6) -> 128-row seg).
  {
    const int k = t & (D1 - 1);
    const int sub = t >> 7;
    const int d0 = sub * D1;
    const float* Wc = W1 + (size_t)(H + d0) * D1 + k;
    float a0 = 0.f, a1 = 0.f, a2 = 0.f, a3 = 0.f;
    #pragma unroll 8
    for (int d = 0; d < 128; d += 4) {
      float w0 = Wc[(size_t)(d + 0) * D1];
      float w1 = Wc[(size_t)(d + 1) * D1];
      float w2 = Wc[(size_t)(d + 2) * D1];
      float w3 = Wc[(size_t)(d + 3) * D1];
      float4 g0 = *reinterpret_cast<const float4*>(&g_crc[0][d0 + d]);
      float4 g1 = *reinterpret_cast<const float4*>(&g_crc[1][d0 + d]);
      float4 g2 = *reinterpret_cast<const float4*>(&g_crc[2][d0 + d]);
      float4 g3 = *reinterpret_cast<const float4*>(&g_crc[3][d0 + d]);
      a0 += g0.x * w0 + g0.y * w1 + g0.z * w2 + g0.w * w3;
      a1 += g1.x * w0 + g1.y * w1 + g1.z * w2 + g1.w * w3;
      a2 += g2.x * w0 + g2.y * w1 + g2.z * w2 + g2.w * w3;
      a3 += g3.x * w0 + g3.y * w1 + g3.z * w2 + g3.w * w3;
    }
    part[3 + sub][0][k] = a0;
    part[3 + sub][1][k] = a1;
    part[3 + sub][2][k] = a2;
    part[3 + sub][3][k] = a3;
  }
  __syncthreads();

  // ---- finalize: wave w owns example e0+w; lane l owns k-pair (l, l+64).
  if (t < 256) {
    const int w = t >> 6, l = t & 63;
    const int e = e0 + w;
    const int k0 = l, k1 = l + 64;
    float h0 = b1[k0], h1 = b1[k1];
    #pragma unroll
    for (int p = 0; p < 9; ++p) {
      h0 += part[p][w][k0];
      h1 += part[p][w][k1];
    }
    h0 = fmaxf(h0, 0.f); h1 = fmaxf(h1, 0.f);
    float v = h0 * W2[k0] + h1 * W2[k1];
    #pragma unroll
    for (int off = 32; off > 0; off >>= 1) v += __shfl_down(v, off);
    if (l == 0) out[e] = 1.0f / (1.0f + expf(-(v + b2[0])));
  }
}

extern "C" void kernel_launch(void* const* d_in, const int* in_sizes, int n_in,
                              void* d_out, int out_size, void* d_ws, size_t ws_size,
                              hipStream_t stream) {
  const float* feat = (const float*)d_in[0];   // [B,S,H] fp32
  const int* start  = (const int*)d_in[1];     // [B]
  const int* endp   = (const int*)d_in[2];     // [B]
  const float* W1   = (const float*)d_in[3];   // [2H,D1]
  const float* b1   = (const float*)d_in[4];   // [D1]
  const float* W2   = (const float*)d_in[5];   // [D1,1]
  const float* b2   = (const float*)d_in[6];   // [1]
  float* out = (float*)d_out;                  // [B]

  hipLaunchKernelGGL(fused_all, dim3(Bn / 4), dim3(768), 0, stream,
                     feat, start, endp, W1, b1, W2, b2, out);
}